// Round 1
// baseline (1582.207 us; speedup 1.0000x reference)
//
#include <hip/hip_runtime.h>
#include <stdint.h>

// Problem constants
#define TT   300          // timesteps
#define NWG  96           // scan workgroups: 32 for layer0, 64 for layer1
#define FLAG_STRIDE 16    // ints per flag slot (64B) to avoid cacheline sharing

// ws layout (in floats)
#define XW0_OFF   0
#define XW0_SZ    (TT*4*1024)            // precomputed x@Wih0.T + biases : 1,228,800
#define H0_OFF    (XW0_OFF + XW0_SZ)
#define HBUF_SZ   (TT*256*4)             // h per t, layout [j][b] : 307,200
#define H1_OFF    (H0_OFF + HBUF_SZ)
#define FLAG_BYTE_OFF ((size_t)(H1_OFF + HBUF_SZ) * 4)
#define FLAG_BYTES    ((size_t)(TT+2)*NWG*FLAG_STRIDE*4)

__device__ __forceinline__ float sigf(float x){ return 1.0f/(1.0f + __expf(-x)); }
__device__ __forceinline__ float tahf(float x){ return 1.0f - 2.0f/(__expf(2.0f*x)+1.0f); }

// ---------------- embedding gather + layer0 input projection --------------
// xw0[t][b][row] = sum_i x[t][b][i]*Wih0[row][i] + bih0[row] + bhh0[row]
// x = emb.reshape(300,4,25) of emb[s][b][e] = encoder[inp[b][s]][e]
__global__ void emb_proj_k(const float* __restrict__ enc, const int* __restrict__ inp,
                           const float* __restrict__ Wih0, const float* __restrict__ bih0,
                           const float* __restrict__ bhh0, float* __restrict__ xw0)
{
  __shared__ float xl[100];
  const int t = blockIdx.x;
  const int tid = threadIdx.x;
  if (tid < 100) {
    int q = t*100 + tid;          // flat index into emb buffer
    int s = q / 1200;
    int rm = q - s*1200;
    int bb = rm / 300;
    int e  = rm - bb*300;
    int tok = inp[bb*25 + s];
    xl[tid] = enc[(long)tok*300 + e];
  }
  __syncthreads();
  for (int rr = 0; rr < 4; ++rr) {
    int row = rr*256 + tid;
    const float* wr = Wih0 + row*25;
    float bias = bih0[row] + bhh0[row];
    float a0 = bias, a1 = bias, a2 = bias, a3 = bias;
#pragma unroll
    for (int i = 0; i < 25; ++i) {
      float w = wr[i];
      a0 += w * xl[i];
      a1 += w * xl[25+i];
      a2 += w * xl[50+i];
      a3 += w * xl[75+i];
    }
    xw0[(t*4+0)*1024 + row] = a0;
    xw0[(t*4+1)*1024 + row] = a1;
    xw0[(t*4+2)*1024 + row] = a2;
    xw0[(t*4+3)*1024 + row] = a3;
  }
}

// ---------------- persistent pipelined 2-layer LSTM scan -------------------
// WG 0..31  : layer0, owns hidden units j in [wg*8, wg*8+8)   (32 gate rows, k=256)
// WG 32..95 : layer1, owns hidden units j in [(wg-32)*4, +4)  (16 gate rows, k=512 = concat(y0,h1))
// Weights resident in VGPRs (16 floats/thread). One device-scope flag barrier
// per super-step; h broadcast through LLC with agent-scope atomics.
__global__ __launch_bounds__(512) void scan_k(
    const float* __restrict__ Whh0, const float* __restrict__ Wih1,
    const float* __restrict__ Whh1, const float* __restrict__ bih1,
    const float* __restrict__ bhh1, const float* __restrict__ h0in,
    const float* __restrict__ c0in, const float* __restrict__ xw0,
    float* __restrict__ h0buf, float* __restrict__ h1buf,
    int* __restrict__ flags, float* __restrict__ dout)
{
  const int wg  = blockIdx.x;
  const int tid = threadIdx.x;
  const int layer = (wg < 32) ? 0 : 1;

  // h staging [k][b] as float4 per k, padded slot = k + (k>>3) so the
  // simultaneous per-wave chunk addresses hit distinct banks.
  __shared__ float4 hst[576];
  __shared__ float4 parts[256];    // per-wave partial sums [wave][row][b]
  __shared__ float  c_lds[32];     // cell state, owned per combine-thread
  __shared__ float  bias_lds[16];  // layer1: bih1+bhh1 for its rows

  float w_[16];
  int c, r;
  if (layer == 0) {
    c = tid >> 5; r = tid & 31;                 // 16 chunks x 32 rows
    int q = r >> 3, jj = r & 7;
    int grow = q*256 + wg*8 + jj;               // global gate row
    const float* wrow = Whh0 + grow*256 + c*16;
#pragma unroll
    for (int m = 0; m < 16; ++m) w_[m] = wrow[m];
    if (tid < 32)                               // c_lds[(jj<<2)|b]
      c_lds[tid] = c0in[(tid&3)*256 + wg*8 + (tid>>2)];
  } else {
    const int w1 = wg - 32;
    c = tid >> 4; r = tid & 15;                 // 32 chunks x 16 rows
    int q = r >> 2, jj = r & 3;
    int grow = q*256 + w1*4 + jj;
    int k0 = c*16;
    const float* wrow = (k0 < 256) ? (Wih1 + grow*256 + k0)
                                   : (Whh1 + grow*256 + (k0 - 256));
#pragma unroll
    for (int m = 0; m < 16; ++m) w_[m] = wrow[m];
    if (tid < 16) {
      int q2 = tid >> 2, jj2 = tid & 3;         // bias_lds[r], r = q*4+jj
      int grow2 = q2*256 + w1*4 + jj2;
      bias_lds[tid] = bih1[grow2] + bhh1[grow2];
      c_lds[tid] = c0in[1024 + (tid&3)*256 + w1*4 + (tid>>2)];
    }
  }
  const int baseslot = c*18;                    // slot of k = c*16

  const int ssBeg = layer ? 1 : 0;
  const int ssEnd = layer ? TT : (TT-1);

  for (int ss = ssBeg; ss <= ssEnd; ++ss) {
    const int t = layer ? (ss-1) : ss;

    // ---- wait for producers of super-step ss-1
    int nw = (layer == 0) ? ((ss >= 1) ? 32 : 0)
                          : ((ss >= 2) ? 96 : 32);
    if (tid < nw && tid != wg) {
      const int* fp = flags + ((size_t)(ss-1)*NWG + tid)*FLAG_STRIDE;
      int guard = 0;
      while (__hip_atomic_load(fp, __ATOMIC_ACQUIRE, __HIP_MEMORY_SCOPE_AGENT) == 0) {
        if (++guard > (1<<20)) break;           // safety bailout (no hang)
      }
    }
    __syncthreads();

    // ---- stage h into LDS (agent-scope loads: LLC-coherent)
    if (layer == 0) {
      int k = tid >> 1, p = tid & 1;            // 512 float2 = 1024 floats
      float2 v;
      if (t > 0) {
        unsigned long long raw = __hip_atomic_load(
            (const unsigned long long*)(h0buf + (size_t)(t-1)*1024 + k*4 + p*2),
            __ATOMIC_RELAXED, __HIP_MEMORY_SCOPE_AGENT);
        union { unsigned long long u; float2 f; } cv; cv.u = raw; v = cv.f;
      } else {
        v.x = h0in[(p*2+0)*256 + k];
        v.y = h0in[(p*2+1)*256 + k];
      }
      int slot = k + (k>>3);
      *(float2*)((float*)&hst[slot] + p*2) = v;
    } else {
#pragma unroll
      for (int it = 0; it < 2; ++it) {
        int u = tid + it*512;                   // 1024 float2 = 2048 floats
        int k = u >> 1, p = u & 1;
        float2 v;
        if (k < 256) {                          // y0[t] part
          unsigned long long raw = __hip_atomic_load(
              (const unsigned long long*)(h0buf + (size_t)t*1024 + k*4 + p*2),
              __ATOMIC_RELAXED, __HIP_MEMORY_SCOPE_AGENT);
          union { unsigned long long u2; float2 f; } cv; cv.u2 = raw; v = cv.f;
        } else {                                // h1[t-1] part
          int k2 = k - 256;
          if (t > 0) {
            unsigned long long raw = __hip_atomic_load(
                (const unsigned long long*)(h1buf + (size_t)(t-1)*1024 + k2*4 + p*2),
                __ATOMIC_RELAXED, __HIP_MEMORY_SCOPE_AGENT);
            union { unsigned long long u2; float2 f; } cv; cv.u2 = raw; v = cv.f;
          } else {
            v.x = h0in[1024 + (p*2+0)*256 + k2];
            v.y = h0in[1024 + (p*2+1)*256 + k2];
          }
        }
        int slot = k + (k>>3);
        *(float2*)((float*)&hst[slot] + p*2) = v;
      }
    }
    __syncthreads();

    // ---- dot products: acc[b] = sum_kk w[kk]*h[k0+kk][b]
    float4 acc; acc.x = 0.f; acc.y = 0.f; acc.z = 0.f; acc.w = 0.f;
#pragma unroll
    for (int m = 0; m < 16; ++m) {
      float4 hv = hst[baseslot + m + (m>>3)];
      acc.x += w_[m]*hv.x;
      acc.y += w_[m]*hv.y;
      acc.z += w_[m]*hv.z;
      acc.w += w_[m]*hv.w;
    }

    // ---- cross-chunk reduction
    if (layer == 0) {
      acc.x += __shfl_xor(acc.x, 32);
      acc.y += __shfl_xor(acc.y, 32);
      acc.z += __shfl_xor(acc.z, 32);
      acc.w += __shfl_xor(acc.w, 32);
      if ((tid & 63) < 32) parts[(tid>>6)*32 + r] = acc;
    } else {
      acc.x += __shfl_xor(acc.x, 16);
      acc.y += __shfl_xor(acc.y, 16);
      acc.z += __shfl_xor(acc.z, 16);
      acc.w += __shfl_xor(acc.w, 16);
      acc.x += __shfl_xor(acc.x, 32);
      acc.y += __shfl_xor(acc.y, 32);
      acc.z += __shfl_xor(acc.z, 32);
      acc.w += __shfl_xor(acc.w, 32);
      if ((tid & 63) < 16) parts[(tid>>6)*16 + r] = acc;
    }
    __syncthreads();

    // ---- combine gates + cell update + broadcast h
    if (layer == 0) {
      if (tid < 32) {
        int jj = tid >> 2, b = tid & 3;
        const float* pf = (const float*)parts;
        float g0=0.f,g1=0.f,g2=0.f,g3=0.f;
#pragma unroll
        for (int wv = 0; wv < 8; ++wv) {
          g0 += pf[(wv*32 +  0 + jj)*4 + b];
          g1 += pf[(wv*32 +  8 + jj)*4 + b];
          g2 += pf[(wv*32 + 16 + jj)*4 + b];
          g3 += pf[(wv*32 + 24 + jj)*4 + b];
        }
        int j = wg*8 + jj;
        const float* xwb = xw0 + (size_t)(t*4 + b)*1024;
        float gi = g0 + xwb[j];
        float gf = g1 + xwb[256 + j];
        float gc = g2 + xwb[512 + j];
        float go = g3 + xwb[768 + j];
        float co = c_lds[tid];
        float cn = sigf(gf)*co + sigf(gi)*tahf(gc);
        float hn = sigf(go)*tahf(cn);
        c_lds[tid] = cn;
        __hip_atomic_store(h0buf + (size_t)t*1024 + j*4 + b, hn,
                           __ATOMIC_RELAXED, __HIP_MEMORY_SCOPE_AGENT);
        if (t == TT-1) {
          dout[400000 + b*256 + j] = hn;          // h_stack layer0
          dout[400000 + 2048 + b*256 + j] = cn;   // c_stack layer0
        }
        asm volatile("s_waitcnt vmcnt(0)" ::: "memory"); // drain before flag
      }
    } else {
      if (tid < 16) {
        int jj = tid >> 2, b = tid & 3;
        const float* pf = (const float*)parts;
        float g0=0.f,g1=0.f,g2=0.f,g3=0.f;
#pragma unroll
        for (int wv = 0; wv < 8; ++wv) {
          g0 += pf[(wv*16 +  0 + jj)*4 + b];
          g1 += pf[(wv*16 +  4 + jj)*4 + b];
          g2 += pf[(wv*16 +  8 + jj)*4 + b];
          g3 += pf[(wv*16 + 12 + jj)*4 + b];
        }
        int j = (wg-32)*4 + jj;
        float gi = g0 + bias_lds[jj];
        float gf = g1 + bias_lds[4 + jj];
        float gc = g2 + bias_lds[8 + jj];
        float go = g3 + bias_lds[12 + jj];
        float co = c_lds[tid];
        float cn = sigf(gf)*co + sigf(gi)*tahf(gc);
        float hn = sigf(go)*tahf(cn);
        c_lds[tid] = cn;
        __hip_atomic_store(h1buf + (size_t)t*1024 + j*4 + b, hn,
                           __ATOMIC_RELAXED, __HIP_MEMORY_SCOPE_AGENT);
        if (t == TT-1) {
          dout[400000 + 1024 + b*256 + j] = hn;        // h_stack layer1
          dout[400000 + 2048 + 1024 + b*256 + j] = cn; // c_stack layer1
        }
        asm volatile("s_waitcnt vmcnt(0)" ::: "memory");
      }
    }
    __syncthreads();
    if (tid == 0) {
      __hip_atomic_store(flags + ((size_t)ss*NWG + wg)*FLAG_STRIDE, 1,
                         __ATOMIC_RELEASE, __HIP_MEMORY_SCOPE_AGENT);
    }
  }
}

// ---------------- fc + relu + vocab decode --------------------------------
__global__ void decode_k(const float* __restrict__ y1buf, const float* __restrict__ fcW,
                         const float* __restrict__ fcb, const float* __restrict__ decW,
                         const float* __restrict__ decb, float* __restrict__ dout)
{
  __shared__ float y1[1024];   // [j][b]
  __shared__ float o10[40];    // [kk][b]
  const int tid = threadIdx.x;
  ((float4*)y1)[tid] = ((const float4*)y1buf)[tid];
  __syncthreads();
  if (tid < 40) {
    int kk = tid >> 2, b = tid & 3;
    float a = fcb[kk];
    for (int j = 0; j < 256; ++j) a += fcW[kk*256 + j] * y1[j*4 + b];
    o10[kk*4 + b] = fmaxf(a, 0.f);
  }
  __syncthreads();
  int v = blockIdx.x*256 + tid;
  if (v < 100000) {
    const float* dr = decW + (size_t)v*10;
    float bias = decb[v];
    float a0 = bias, a1 = bias, a2 = bias, a3 = bias;
#pragma unroll
    for (int kk = 0; kk < 10; ++kk) {
      float w = dr[kk];
      a0 += w * o10[kk*4+0];
      a1 += w * o10[kk*4+1];
      a2 += w * o10[kk*4+2];
      a3 += w * o10[kk*4+3];
    }
    float4 o; o.x = a0; o.y = a1; o.z = a2; o.w = a3;
    ((float4*)dout)[v] = o;   // decoded.T[v][0..3]
  }
}

extern "C" void kernel_launch(void* const* d_in, const int* in_sizes, int n_in,
                              void* d_out, int out_size, void* d_ws, size_t ws_size,
                              hipStream_t stream)
{
  const float* enc  = (const float*)d_in[0];
  const float* h0in = (const float*)d_in[1];
  const float* c0in = (const float*)d_in[2];
  const float* Wih0 = (const float*)d_in[3];
  const float* Whh0 = (const float*)d_in[4];
  const float* bih0 = (const float*)d_in[5];
  const float* bhh0 = (const float*)d_in[6];
  const float* Wih1 = (const float*)d_in[7];
  const float* Whh1 = (const float*)d_in[8];
  const float* bih1 = (const float*)d_in[9];
  const float* bhh1 = (const float*)d_in[10];
  const float* fcW  = (const float*)d_in[11];
  const float* fcb  = (const float*)d_in[12];
  const float* decW = (const float*)d_in[13];
  const float* decb = (const float*)d_in[14];
  const int*   inp  = (const int*)d_in[15];

  float* ws    = (float*)d_ws;
  float* xw0   = ws + XW0_OFF;
  float* h0buf = ws + H0_OFF;
  float* h1buf = ws + H1_OFF;
  int*   flags = (int*)((char*)d_ws + FLAG_BYTE_OFF);
  float* dout  = (float*)d_out;

  hipMemsetAsync(flags, 0, FLAG_BYTES, stream);
  emb_proj_k<<<TT, 256, 0, stream>>>(enc, inp, Wih0, bih0, bhh0, xw0);
  scan_k<<<NWG, 512, 0, stream>>>(Whh0, Wih1, Whh1, bih1, bhh1,
                                  h0in, c0in, xw0, h0buf, h1buf, flags, dout);
  decode_k<<<(100000 + 255)/256, 256, 0, stream>>>(h1buf + 299*1024, fcW, fcb,
                                                   decW, decb, dout);
}

// Round 2
// 591.472 us; speedup vs baseline: 2.6750x; 2.6750x over previous
//
#include <hip/hip_runtime.h>
#include <stdint.h>

// Problem constants
#define TT   300          // timesteps
#define NWG  96           // scan workgroups: 32 for layer0, 64 for layer1

// ws layout (in floats)
// xw0:  precomputed x@Wih0.T + biases          : TT*4*1024
// hp0:  layer0 h as {float,tag} pairs per t    : TT*1024 pairs = TT*2048 floats
// hp1:  layer1 h pairs                          : TT*2048 floats
#define XW0_OFF   0
#define XW0_SZ    (TT*4*1024)
#define HP0_OFF   (XW0_OFF + XW0_SZ)
#define HP_SZ     (TT*1024*2)
#define HP1_OFF   (HP0_OFF + HP_SZ)
#define HP_BYTES  ((size_t)HP_SZ * 2 * 4)

__device__ __forceinline__ float sigf(float x){ return 1.0f/(1.0f + __expf(-x)); }
__device__ __forceinline__ float tahf(float x){ return 1.0f - 2.0f/(__expf(2.0f*x)+1.0f); }

// LLC-coherent raw loads (bypass L1+L2; no cache invalidates, unlike acquire)
__device__ __forceinline__ uint4 llc_load16(const float* p) {
  uint4 v;
  asm volatile("global_load_dwordx4 %0, %1, off sc0 sc1\n\t"
               "s_waitcnt vmcnt(0)"
               : "=v"(v) : "v"(p) : "memory");
  return v;
}
__device__ __forceinline__ void llc_load32(const float* p, uint4& a, uint4& b) {
  asm volatile("global_load_dwordx4 %0, %2, off sc0 sc1\n\t"
               "global_load_dwordx4 %1, %2, off offset:16 sc0 sc1\n\t"
               "s_waitcnt vmcnt(0)"
               : "=&v"(a), "=&v"(b) : "v"(p) : "memory");
}
// packed {h, tag} single 8B store -> data+flag become visible atomically
__device__ __forceinline__ void llc_store_pair(float* p, float h, unsigned tag) {
  union { struct { float h; unsigned t; } s; unsigned long long u; } pk;
  pk.s.h = h; pk.s.t = tag;
  __hip_atomic_store((unsigned long long*)p, pk.u,
                     __ATOMIC_RELAXED, __HIP_MEMORY_SCOPE_AGENT);
}

// ---------------- embedding gather + layer0 input projection --------------
__global__ void emb_proj_k(const float* __restrict__ enc, const int* __restrict__ inp,
                           const float* __restrict__ Wih0, const float* __restrict__ bih0,
                           const float* __restrict__ bhh0, float* __restrict__ xw0)
{
  __shared__ float xl[100];
  const int t = blockIdx.x;
  const int tid = threadIdx.x;
  if (tid < 100) {
    int q = t*100 + tid;          // flat index into emb buffer
    int s = q / 1200;
    int rm = q - s*1200;
    int bb = rm / 300;
    int e  = rm - bb*300;
    int tok = inp[bb*25 + s];
    xl[tid] = enc[(long)tok*300 + e];
  }
  __syncthreads();
  for (int rr = 0; rr < 4; ++rr) {
    int row = rr*256 + tid;
    const float* wr = Wih0 + row*25;
    float bias = bih0[row] + bhh0[row];
    float a0 = bias, a1 = bias, a2 = bias, a3 = bias;
#pragma unroll
    for (int i = 0; i < 25; ++i) {
      float w = wr[i];
      a0 += w * xl[i];
      a1 += w * xl[25+i];
      a2 += w * xl[50+i];
      a3 += w * xl[75+i];
    }
    xw0[(t*4+0)*1024 + row] = a0;
    xw0[(t*4+1)*1024 + row] = a1;
    xw0[(t*4+2)*1024 + row] = a2;
    xw0[(t*4+3)*1024 + row] = a3;
  }
}

// ---------------- persistent pipelined 2-layer LSTM scan -------------------
// WG 0..31  : layer0, hidden units j in [wg*8, wg*8+8)   (32 gate rows, k=256)
// WG 32..95 : layer1, hidden units j in [(wg-32)*4, +4)  (16 gate rows, k=512)
// Weights live in VGPRs. Sync: consumers poll the {h,tag} pairs directly.
__global__ __launch_bounds__(512) void scan_k(
    const float* __restrict__ Whh0, const float* __restrict__ Wih1,
    const float* __restrict__ Whh1, const float* __restrict__ bih1,
    const float* __restrict__ bhh1, const float* __restrict__ h0in,
    const float* __restrict__ c0in, const float* __restrict__ xw0,
    float* __restrict__ hp0, float* __restrict__ hp1,
    float* __restrict__ dout)
{
  const int wg  = blockIdx.x;
  const int tid = threadIdx.x;
  const int layer = (wg < 32) ? 0 : 1;

  __shared__ float4 hst[576];      // h staging [k][b], slot = k + (k>>3)
  __shared__ float4 parts[256];    // per-wave partials [wave][row][b]
  __shared__ float  c_lds[32];     // cell state, 1 owner thread each
  __shared__ float  bias_lds[16];  // layer1: bih1+bhh1 for its rows

  float w_[16];
  int c, r;
  if (layer == 0) {
    c = tid >> 5; r = tid & 31;                 // 16 chunks x 32 rows
    int q = r >> 3, jj = r & 7;
    int grow = q*256 + wg*8 + jj;
    const float* wrow = Whh0 + grow*256 + c*16;
#pragma unroll
    for (int m = 0; m < 16; ++m) w_[m] = wrow[m];
    if (tid < 32)
      c_lds[tid] = c0in[(tid&3)*256 + wg*8 + (tid>>2)];
  } else {
    const int w1 = wg - 32;
    c = tid >> 4; r = tid & 15;                 // 32 chunks x 16 rows
    int q = r >> 2, jj = r & 3;
    int grow = q*256 + w1*4 + jj;
    int k0 = c*16;
    const float* wrow = (k0 < 256) ? (Wih1 + grow*256 + k0)
                                   : (Whh1 + grow*256 + (k0 - 256));
#pragma unroll
    for (int m = 0; m < 16; ++m) w_[m] = wrow[m];
    if (tid < 16) {
      int q2 = tid >> 2, jj2 = tid & 3;
      int grow2 = q2*256 + w1*4 + jj2;
      bias_lds[tid] = bih1[grow2] + bhh1[grow2];
      c_lds[tid] = c0in[1024 + (tid&3)*256 + w1*4 + (tid>>2)];
    }
  }
  const int baseslot = c*18;

  const int ssBeg = layer ? 1 : 0;
  const int ssEnd = layer ? TT : (TT-1);

  for (int ss = ssBeg; ss <= ssEnd; ++ss) {
    const int t = layer ? (ss-1) : ss;

    // ---- prefetch gate input-projection rows (latency hides under poll)
    float xwi=0.f, xwf=0.f, xwg=0.f, xwo=0.f;
    if (layer == 0 && tid < 32) {
      int j = wg*8 + (tid>>2);
      const float* xwb = xw0 + (size_t)(t*4 + (tid&3))*1024;
      xwi = xwb[j]; xwf = xwb[256+j]; xwg = xwb[512+j]; xwo = xwb[768+j];
    }

    // ---- stage h into LDS, polling {h,tag} pairs (data IS the flag)
    if (layer == 0) {
      int k = tid >> 1, half = tid & 1;         // pair idx = tid*2, tid*2+1
      float2 v;
      if (t > 0) {
        const float* pp = hp0 + ((size_t)(t-1)*1024 + (size_t)tid*2)*2;
        const unsigned tg = (unsigned)t;        // producer wrote tag = (t-1)+1
        unsigned guard = 0;
        uint4 q;
        do { q = llc_load16(pp); }
        while ((q.y != tg || q.w != tg) && ++guard < (1u<<20));
        v.x = __uint_as_float(q.x);
        v.y = __uint_as_float(q.z);
      } else {
        v.x = h0in[(half*2+0)*256 + k];
        v.y = h0in[(half*2+1)*256 + k];
      }
      int slot = k + (k>>3);
      *(float2*)((float*)&hst[slot] + half*2) = v;
    } else {
      int k = tid;                              // one k per thread, 4 pairs
      float4 v;
      if (k < 256) {                            // y0[t] from hp0[t]
        const float* pp = hp0 + ((size_t)t*1024 + (size_t)k*4)*2;
        const unsigned tg = (unsigned)(t+1);
        unsigned guard = 0;
        uint4 q1, q2;
        do { llc_load32(pp, q1, q2); }
        while ((q1.y != tg || q1.w != tg || q2.y != tg || q2.w != tg) &&
               ++guard < (1u<<20));
        v.x = __uint_as_float(q1.x); v.y = __uint_as_float(q1.z);
        v.z = __uint_as_float(q2.x); v.w = __uint_as_float(q2.z);
      } else {
        int k2 = k - 256;                       // h1[t-1]
        if (t > 0) {
          const float* pp = hp1 + ((size_t)(t-1)*1024 + (size_t)k2*4)*2;
          const unsigned tg = (unsigned)t;
          unsigned guard = 0;
          uint4 q1, q2;
          do { llc_load32(pp, q1, q2); }
          while ((q1.y != tg || q1.w != tg || q2.y != tg || q2.w != tg) &&
                 ++guard < (1u<<20));
          v.x = __uint_as_float(q1.x); v.y = __uint_as_float(q1.z);
          v.z = __uint_as_float(q2.x); v.w = __uint_as_float(q2.z);
        } else {
          v.x = h0in[1024 + 0*256 + k2];
          v.y = h0in[1024 + 1*256 + k2];
          v.z = h0in[1024 + 2*256 + k2];
          v.w = h0in[1024 + 3*256 + k2];
        }
      }
      int slot = k + (k>>3);
      hst[slot] = v;
    }
    __syncthreads();

    // ---- dot products: acc[b] = sum_kk w[kk]*h[k0+kk][b]
    float4 acc; acc.x = 0.f; acc.y = 0.f; acc.z = 0.f; acc.w = 0.f;
#pragma unroll
    for (int m = 0; m < 16; ++m) {
      float4 hv = hst[baseslot + m + (m>>3)];
      acc.x += w_[m]*hv.x;
      acc.y += w_[m]*hv.y;
      acc.z += w_[m]*hv.z;
      acc.w += w_[m]*hv.w;
    }

    // ---- cross-chunk reduction
    if (layer == 0) {
      acc.x += __shfl_xor(acc.x, 32);
      acc.y += __shfl_xor(acc.y, 32);
      acc.z += __shfl_xor(acc.z, 32);
      acc.w += __shfl_xor(acc.w, 32);
      if ((tid & 63) < 32) parts[(tid>>6)*32 + r] = acc;
    } else {
      acc.x += __shfl_xor(acc.x, 16);
      acc.y += __shfl_xor(acc.y, 16);
      acc.z += __shfl_xor(acc.z, 16);
      acc.w += __shfl_xor(acc.w, 16);
      acc.x += __shfl_xor(acc.x, 32);
      acc.y += __shfl_xor(acc.y, 32);
      acc.z += __shfl_xor(acc.z, 32);
      acc.w += __shfl_xor(acc.w, 32);
      if ((tid & 63) < 16) parts[(tid>>6)*16 + r] = acc;
    }
    __syncthreads();

    // ---- combine gates + cell update + broadcast {h,tag}
    if (layer == 0) {
      if (tid < 32) {
        int jj = tid >> 2, b = tid & 3;
        const float* pf = (const float*)parts;
        float g0=0.f,g1=0.f,g2=0.f,g3=0.f;
#pragma unroll
        for (int wv = 0; wv < 8; ++wv) {
          g0 += pf[(wv*32 +  0 + jj)*4 + b];
          g1 += pf[(wv*32 +  8 + jj)*4 + b];
          g2 += pf[(wv*32 + 16 + jj)*4 + b];
          g3 += pf[(wv*32 + 24 + jj)*4 + b];
        }
        int j = wg*8 + jj;
        float gi = g0 + xwi;
        float gf = g1 + xwf;
        float gc = g2 + xwg;
        float go = g3 + xwo;
        float co = c_lds[tid];
        float cn = sigf(gf)*co + sigf(gi)*tahf(gc);
        float hn = sigf(go)*tahf(cn);
        c_lds[tid] = cn;
        llc_store_pair(hp0 + ((size_t)t*1024 + j*4 + b)*2, hn, (unsigned)(t+1));
        if (t == TT-1) {
          dout[400000 + b*256 + j] = hn;          // h_stack layer0
          dout[400000 + 2048 + b*256 + j] = cn;   // c_stack layer0
        }
      }
    } else {
      if (tid < 16) {
        int jj = tid >> 2, b = tid & 3;
        const float* pf = (const float*)parts;
        float g0=0.f,g1=0.f,g2=0.f,g3=0.f;
#pragma unroll
        for (int wv = 0; wv < 8; ++wv) {
          g0 += pf[(wv*16 +  0 + jj)*4 + b];
          g1 += pf[(wv*16 +  4 + jj)*4 + b];
          g2 += pf[(wv*16 +  8 + jj)*4 + b];
          g3 += pf[(wv*16 + 12 + jj)*4 + b];
        }
        int j = (wg-32)*4 + jj;
        float gi = g0 + bias_lds[jj];
        float gf = g1 + bias_lds[4 + jj];
        float gc = g2 + bias_lds[8 + jj];
        float go = g3 + bias_lds[12 + jj];
        float co = c_lds[tid];
        float cn = sigf(gf)*co + sigf(gi)*tahf(gc);
        float hn = sigf(go)*tahf(cn);
        c_lds[tid] = cn;
        llc_store_pair(hp1 + ((size_t)t*1024 + j*4 + b)*2, hn, (unsigned)(t+1));
        if (t == TT-1) {
          dout[400000 + 1024 + b*256 + j] = hn;        // h_stack layer1
          dout[400000 + 2048 + 1024 + b*256 + j] = cn; // c_stack layer1
        }
      }
    }
    __syncthreads();
  }
}

// ---------------- fc + relu + vocab decode --------------------------------
__global__ void decode_k(const float* __restrict__ y1p, const float* __restrict__ fcW,
                         const float* __restrict__ fcb, const float* __restrict__ decW,
                         const float* __restrict__ decb, float* __restrict__ dout)
{
  __shared__ float y1[1024];   // [j][b]
  __shared__ float o10[40];    // [kk][b]
  const int tid = threadIdx.x;
#pragma unroll
  for (int b = 0; b < 4; ++b)
    y1[tid*4 + b] = y1p[(size_t)(tid*4 + b)*2];   // strip tags
  __syncthreads();
  if (tid < 40) {
    int kk = tid >> 2, b = tid & 3;
    float a = fcb[kk];
    for (int j = 0; j < 256; ++j) a += fcW[kk*256 + j] * y1[j*4 + b];
    o10[kk*4 + b] = fmaxf(a, 0.f);
  }
  __syncthreads();
  int v = blockIdx.x*256 + tid;
  if (v < 100000) {
    const float* dr = decW + (size_t)v*10;
    float bias = decb[v];
    float a0 = bias, a1 = bias, a2 = bias, a3 = bias;
#pragma unroll
    for (int kk = 0; kk < 10; ++kk) {
      float w = dr[kk];
      a0 += w * o10[kk*4+0];
      a1 += w * o10[kk*4+1];
      a2 += w * o10[kk*4+2];
      a3 += w * o10[kk*4+3];
    }
    float4 o; o.x = a0; o.y = a1; o.z = a2; o.w = a3;
    ((float4*)dout)[v] = o;   // decoded.T[v][0..3]
  }
}

extern "C" void kernel_launch(void* const* d_in, const int* in_sizes, int n_in,
                              void* d_out, int out_size, void* d_ws, size_t ws_size,
                              hipStream_t stream)
{
  const float* enc  = (const float*)d_in[0];
  const float* h0in = (const float*)d_in[1];
  const float* c0in = (const float*)d_in[2];
  const float* Wih0 = (const float*)d_in[3];
  const float* Whh0 = (const float*)d_in[4];
  const float* bih0 = (const float*)d_in[5];
  const float* bhh0 = (const float*)d_in[6];
  const float* Wih1 = (const float*)d_in[7];
  const float* Whh1 = (const float*)d_in[8];
  const float* bih1 = (const float*)d_in[9];
  const float* bhh1 = (const float*)d_in[10];
  const float* fcW  = (const float*)d_in[11];
  const float* fcb  = (const float*)d_in[12];
  const float* decW = (const float*)d_in[13];
  const float* decb = (const float*)d_in[14];
  const int*   inp  = (const int*)d_in[15];

  float* ws   = (float*)d_ws;
  float* xw0  = ws + XW0_OFF;
  float* hp0  = ws + HP0_OFF;
  float* hp1  = ws + HP1_OFF;
  float* dout = (float*)d_out;

  // zero all tags (valid tags are >= 1) -> replay-safe
  hipMemsetAsync(hp0, 0, HP_BYTES, stream);
  emb_proj_k<<<TT, 256, 0, stream>>>(enc, inp, Wih0, bih0, bhh0, xw0);
  scan_k<<<NWG, 512, 0, stream>>>(Whh0, Wih1, Whh1, bih1, bhh1,
                                  h0in, c0in, xw0, hp0, hp1, dout);
  decode_k<<<(100000 + 255)/256, 256, 0, stream>>>(hp1 + (size_t)(TT-1)*1024*2,
                                                   fcW, fcb, decW, decb, dout);
}